// Round 3
// baseline (163.085 us; speedup 1.0000x reference)
//
#include <hip/hip_runtime.h>
#include <hip/hip_bf16.h>

// out = x @ W^T + bias (memristor constants cancel exactly; see round-0).
// M=512, N=2048, K=2048 fp32 -> bf16 MFMA, fp32 accum.
//
// Round-3: fix the pipeline. __syncthreads drains vmcnt(0), so loads issued
// just before the barrier (round-2) expose full L2 latency every iteration.
// Now: tile t+2's global loads are issued at the TOP of iteration t (dual
// register sets), giving them the whole compute+stage phase to land before
// the barrier drain. 512 thr = 8 waves = 2x2 spatial x 2-way K-split,
// BK=128, dbuf LDS, one barrier/iter.

typedef float  float4_t __attribute__((ext_vector_type(4)));
typedef short  short8_t __attribute__((ext_vector_type(8)));
typedef float  floatx4  __attribute__((ext_vector_type(4)));

constexpr int M = 512, N = 2048, K = 2048;
constexpr int BM = 64, BN = 64, BK = 128;
constexpr int LDK = BK + 8;           // 136 bf16 = 272 B row stride; fragment reads 2-way (free)
constexpr int NT  = K / BK;           // 16 k-tiles

__global__ __launch_bounds__(512)
void memristor_gemm(const float* __restrict__ x, const float* __restrict__ w,
                    const float* __restrict__ bias, float* __restrict__ out)
{
    __shared__ __hip_bfloat16 As[2][BM][LDK];
    __shared__ __hip_bfloat16 Bs[2][BN][LDK];

    const int tid  = threadIdx.x;
    const int bn   = blockIdx.x, bm = blockIdx.y;
    const int lane = tid & 63;
    const int wave = tid >> 6;        // 0..7
    const int wsp  = wave & 3;        // spatial quadrant (2x2 of 32x32)
    const int kp   = wave >> 2;       // k-half
    const int wm   = (wsp >> 1) * 32;
    const int wn   = (wsp & 1) * 32;
    const int l16  = lane & 15;
    const int quad = lane >> 4;

    // staging map: 64 rows x 32 float4 per matrix; 512 thr -> 4 row-rounds
    const int srow = tid >> 5;        // 0..15
    const int sc4  = tid & 31;        // float4 column

    const float* xp = x + (size_t)(bm * BM + srow) * K + sc4 * 4;
    const float* wp = w + (size_t)(bn * BN + srow) * K + sc4 * 4;

    floatx4 acc[2][2];
    #pragma unroll
    for (int i = 0; i < 2; ++i)
        #pragma unroll
        for (int j = 0; j < 2; ++j)
            acc[i][j] = (floatx4){0.f, 0.f, 0.f, 0.f};

    // dual prefetch register sets: [set][0..3]=A rows, [4..7]=B rows
    float4_t rg[2][8];

    auto load_tile = [&](int set, int t) {
        #pragma unroll
        for (int r = 0; r < 4; ++r) {
            rg[set][r]     = *(const float4_t*)(xp + (size_t)r * 16 * K + t * BK);
            rg[set][4 + r] = *(const float4_t*)(wp + (size_t)r * 16 * K + t * BK);
        }
    };

    auto stage = [&](int set, int buf) {
        #pragma unroll
        for (int r = 0; r < 4; ++r) {
            const int row = r * 16 + srow;
            union { __hip_bfloat16 h[4]; unsigned long long u; } ua, ub;
            ua.h[0] = __float2bfloat16(rg[set][r].x);
            ua.h[1] = __float2bfloat16(rg[set][r].y);
            ua.h[2] = __float2bfloat16(rg[set][r].z);
            ua.h[3] = __float2bfloat16(rg[set][r].w);
            ub.h[0] = __float2bfloat16(rg[set][4 + r].x);
            ub.h[1] = __float2bfloat16(rg[set][4 + r].y);
            ub.h[2] = __float2bfloat16(rg[set][4 + r].z);
            ub.h[3] = __float2bfloat16(rg[set][4 + r].w);
            *(unsigned long long*)&As[buf][row][sc4 * 4] = ua.u;   // ds_write_b64
            *(unsigned long long*)&Bs[buf][row][sc4 * 4] = ub.u;
        }
    };

    auto compute = [&](int buf) {
        #pragma unroll
        for (int s = 0; s < 2; ++s) {
            const int kb = kp * 64 + s * 32 + quad * 8;
            short8_t af[2], bf[2];
            af[0] = *(const short8_t*)&As[buf][wm + l16][kb];
            af[1] = *(const short8_t*)&As[buf][wm + 16 + l16][kb];
            bf[0] = *(const short8_t*)&Bs[buf][wn + l16][kb];
            bf[1] = *(const short8_t*)&Bs[buf][wn + 16 + l16][kb];
            #pragma unroll
            for (int i = 0; i < 2; ++i)
                #pragma unroll
                for (int j = 0; j < 2; ++j)
                    acc[i][j] = __builtin_amdgcn_mfma_f32_16x16x32_bf16(
                        af[i], bf[j], acc[i][j], 0, 0, 0);
        }
    };

    // --- prologue ---
    load_tile(0, 0);
    stage(0, 0);
    load_tile(1, 1);                  // drained by the first barrier (once, cheap)
    __syncthreads();

    // --- main loop: iter t computes tile t from LDS[t&1].
    // set ownership: at top of iter t, set[(t+1)&1] holds tile t+1 (arrived),
    // set[t&1] is free -> receives tile t+2. Loads get compute+stage time
    // to land before the barrier's vmcnt(0) drain.
    for (int t = 0; t < NT; ++t) {
        const int cur = t & 1;
        if (t + 2 < NT) load_tile(cur, t + 2);
        compute(cur);
        if (t + 1 < NT) stage(cur ^ 1, cur ^ 1);
        __syncthreads();
    }

    // --- epilogue: 2-way K-split reduction through LDS ---
    float* scrb = (float*)&As[0][0][0];   // 18432 B scratch (compute all done)
    if (kp == 1) {
        #pragma unroll
        for (int i = 0; i < 2; ++i)
            #pragma unroll
            for (int j = 0; j < 2; ++j) {
                float* p = scrb + ((wsp * 32 + j * 16 + l16) * 36 + i * 16 + quad * 4);
                *(floatx4*)p = acc[i][j];
            }
    }
    __syncthreads();
    if (kp == 0) {
        #pragma unroll
        for (int j = 0; j < 2; ++j) {
            const int col = bn * BN + wn + j * 16 + l16;
            const float bv = bias[col];
            #pragma unroll
            for (int i = 0; i < 2; ++i) {
                const floatx4 part = *(const floatx4*)(
                    scrb + ((wsp * 32 + j * 16 + l16) * 36 + i * 16 + quad * 4));
                const int row0 = bm * BM + wm + i * 16 + quad * 4;
                #pragma unroll
                for (int r = 0; r < 4; ++r)
                    out[(size_t)(row0 + r) * N + col] = acc[i][j][r] + part[r] + bv;
            }
        }
    }
}

extern "C" void kernel_launch(void* const* d_in, const int* in_sizes, int n_in,
                              void* d_out, int out_size, void* d_ws, size_t ws_size,
                              hipStream_t stream) {
    const float* x    = (const float*)d_in[0];   // (512, 2048)
    const float* w    = (const float*)d_in[1];   // (2048, 2048) = (N, K)
    const float* bias = (const float*)d_in[2];   // (2048,)
    float* out = (float*)d_out;                  // (512, 2048)

    dim3 grid(N / BN, M / BM);                   // (32, 8) = 256 blocks, 1 per CU
    memristor_gemm<<<grid, 512, 0, stream>>>(x, w, bias, out);
}

// Round 4
// 82.287 us; speedup vs baseline: 1.9819x; 1.9819x over previous
//
#include <hip/hip_runtime.h>
#include <hip/hip_bf16.h>

// out = x @ W^T + bias (memristor constants cancel exactly; see round-0).
// M=512, N=2048, K=2048 fp32 -> bf16 MFMA, fp32 accum.
//
// Round-4: round-3's rg[2][8] with RUNTIME set index was demoted to scratch
// (WRITE_SIZE 266 MB, VGPR=56 -> spills). Same pipeline, but the main loop is
// manually unrolled x2 with NAMED register sets and compile-time buffer
// indices so everything stays in VGPRs. 512 thr = 8 waves = 2x2 spatial x
// 2-way K-split, BK=128, dbuf LDS, loads for tile t+2 issued at top of iter t.

typedef float  float4_t __attribute__((ext_vector_type(4)));
typedef short  short8_t __attribute__((ext_vector_type(8)));
typedef float  floatx4  __attribute__((ext_vector_type(4)));

constexpr int M = 512, N = 2048, K = 2048;
constexpr int BM = 64, BN = 64, BK = 128;
constexpr int LDK = BK + 8;           // 136 bf16 = 272 B row stride
constexpr int NT  = K / BK;           // 16 k-tiles (even)

__global__ __launch_bounds__(512)
void memristor_gemm(const float* __restrict__ x, const float* __restrict__ w,
                    const float* __restrict__ bias, float* __restrict__ out)
{
    __shared__ __hip_bfloat16 As[2][BM][LDK];
    __shared__ __hip_bfloat16 Bs[2][BN][LDK];

    const int tid  = threadIdx.x;
    const int bn   = blockIdx.x, bm = blockIdx.y;
    const int lane = tid & 63;
    const int wave = tid >> 6;        // 0..7
    const int wsp  = wave & 3;        // spatial quadrant (2x2 of 32x32)
    const int kp   = wave >> 2;       // k-half
    const int wm   = (wsp >> 1) * 32;
    const int wn   = (wsp & 1) * 32;
    const int l16  = lane & 15;
    const int quad = lane >> 4;

    // staging map: 64 rows x 32 float4 per matrix; 512 thr -> 4 row-rounds
    const int srow = tid >> 5;        // 0..15
    const int sc4  = tid & 31;        // float4 column

    const float* xp = x + (size_t)(bm * BM + srow) * K + sc4 * 4;
    const float* wp = w + (size_t)(bn * BN + srow) * K + sc4 * 4;

    floatx4 acc[2][2];
    #pragma unroll
    for (int i = 0; i < 2; ++i)
        #pragma unroll
        for (int j = 0; j < 2; ++j)
            acc[i][j] = (floatx4){0.f, 0.f, 0.f, 0.f};

    // two NAMED prefetch register sets -- all indexing compile-time constant
    float4_t a0[4], b0[4], a1[4], b1[4];

#define LOAD_TILE(A_, B_, t_)                                                 \
    {                                                                         \
        _Pragma("unroll")                                                     \
        for (int r = 0; r < 4; ++r) {                                         \
            A_[r] = *(const float4_t*)(xp + (size_t)(r * 16) * K + (t_) * BK);\
            B_[r] = *(const float4_t*)(wp + (size_t)(r * 16) * K + (t_) * BK);\
        }                                                                     \
    }

#define STAGE(A_, B_, buf_)                                                   \
    {                                                                         \
        _Pragma("unroll")                                                     \
        for (int r = 0; r < 4; ++r) {                                         \
            const int row = r * 16 + srow;                                    \
            union { __hip_bfloat16 h[4]; unsigned long long u; } ua, ub;      \
            ua.h[0] = __float2bfloat16(A_[r].x);                              \
            ua.h[1] = __float2bfloat16(A_[r].y);                              \
            ua.h[2] = __float2bfloat16(A_[r].z);                              \
            ua.h[3] = __float2bfloat16(A_[r].w);                              \
            ub.h[0] = __float2bfloat16(B_[r].x);                              \
            ub.h[1] = __float2bfloat16(B_[r].y);                              \
            ub.h[2] = __float2bfloat16(B_[r].z);                              \
            ub.h[3] = __float2bfloat16(B_[r].w);                              \
            *(unsigned long long*)&As[buf_][row][sc4 * 4] = ua.u;             \
            *(unsigned long long*)&Bs[buf_][row][sc4 * 4] = ub.u;             \
        }                                                                     \
    }

#define COMPUTE(buf_)                                                         \
    {                                                                         \
        _Pragma("unroll")                                                     \
        for (int s = 0; s < 2; ++s) {                                         \
            const int kb = kp * 64 + s * 32 + quad * 8;                       \
            short8_t af0 = *(const short8_t*)&As[buf_][wm + l16][kb];         \
            short8_t af1 = *(const short8_t*)&As[buf_][wm + 16 + l16][kb];    \
            short8_t bf0 = *(const short8_t*)&Bs[buf_][wn + l16][kb];         \
            short8_t bf1 = *(const short8_t*)&Bs[buf_][wn + 16 + l16][kb];    \
            acc[0][0] = __builtin_amdgcn_mfma_f32_16x16x32_bf16(af0, bf0, acc[0][0], 0, 0, 0); \
            acc[0][1] = __builtin_amdgcn_mfma_f32_16x16x32_bf16(af0, bf1, acc[0][1], 0, 0, 0); \
            acc[1][0] = __builtin_amdgcn_mfma_f32_16x16x32_bf16(af1, bf0, acc[1][0], 0, 0, 0); \
            acc[1][1] = __builtin_amdgcn_mfma_f32_16x16x32_bf16(af1, bf1, acc[1][1], 0, 0, 0); \
        }                                                                     \
    }

    // --- prologue ---
    LOAD_TILE(a0, b0, 0)
    STAGE(a0, b0, 0)
    LOAD_TILE(a1, b1, 1)              // drained once by the first barrier
    __syncthreads();

    // --- main loop, unrolled x2: set/buffer indices all compile-time ---
    for (int t = 0; t < NT; t += 2) {
        // even half: compute tile t from buf0; a0 is free (tile t staged)
        if (t + 2 < NT) LOAD_TILE(a0, b0, t + 2)
        COMPUTE(0)
        STAGE(a1, b1, 1)              // tile t+1 -> buf1
        __syncthreads();
        // odd half: compute tile t+1 from buf1; a1 free
        if (t + 3 < NT) LOAD_TILE(a1, b1, t + 3)
        COMPUTE(1)
        if (t + 2 < NT) STAGE(a0, b0, 0)  // tile t+2 -> buf0
        __syncthreads();
    }

    // --- epilogue: 2-way K-split reduction through LDS (As reused) ---
    float* scrb = (float*)&As[0][0][0];   // 18432 B scratch; all LDS reads done
    if (kp == 1) {
        #pragma unroll
        for (int i = 0; i < 2; ++i)
            #pragma unroll
            for (int j = 0; j < 2; ++j) {
                float* p = scrb + ((wsp * 32 + j * 16 + l16) * 36 + i * 16 + quad * 4);
                *(floatx4*)p = acc[i][j];
            }
    }
    __syncthreads();
    if (kp == 0) {
        #pragma unroll
        for (int j = 0; j < 2; ++j) {
            const int col = bn * BN + wn + j * 16 + l16;
            const float bv = bias[col];
            #pragma unroll
            for (int i = 0; i < 2; ++i) {
                const floatx4 part = *(const floatx4*)(
                    scrb + ((wsp * 32 + j * 16 + l16) * 36 + i * 16 + quad * 4));
                const int row0 = bm * BM + wm + i * 16 + quad * 4;
                #pragma unroll
                for (int r = 0; r < 4; ++r)
                    out[(size_t)(row0 + r) * N + col] = acc[i][j][r] + part[r] + bv;
            }
        }
    }
#undef LOAD_TILE
#undef STAGE
#undef COMPUTE
}

extern "C" void kernel_launch(void* const* d_in, const int* in_sizes, int n_in,
                              void* d_out, int out_size, void* d_ws, size_t ws_size,
                              hipStream_t stream) {
    const float* x    = (const float*)d_in[0];   // (512, 2048)
    const float* w    = (const float*)d_in[1];   // (2048, 2048) = (N, K)
    const float* bias = (const float*)d_in[2];   // (2048,)
    float* out = (float*)d_out;                  // (512, 2048)

    dim3 grid(N / BN, M / BM);                   // (32, 8) = 256 blocks, 1 per CU
    memristor_gemm<<<grid, 512, 0, stream>>>(x, w, bias, out);
}